// Round 2
// baseline (241.660 us; speedup 1.0000x reference)
//
#include <hip/hip_runtime.h>
#include <hip/hip_bf16.h>

#define D_MODEL 1024
#define N_HEADS 16
#define HEAD_DIM 64
#define SEQ 2048
#define BATCH 2

typedef __attribute__((ext_vector_type(8))) short bf16x8;
typedef __attribute__((ext_vector_type(4))) float f32x4;

typedef __attribute__((address_space(3))) unsigned lds_uint;
typedef __attribute__((address_space(1))) const unsigned global_cuint;

__device__ __forceinline__ void async_cp16(const ushort* g, ushort* l) {
  __builtin_amdgcn_global_load_lds((global_cuint*)g, (lds_uint*)l, 16, 0, 0);
}

__device__ __forceinline__ ushort f2b(float f) {
  union { float f; unsigned u; } x; x.f = f;
  unsigned r = x.u + 0x7fffu + ((x.u >> 16) & 1u);
  return (ushort)(r >> 16);
}

// packed f32x2 -> bf16x2; low word = a
__device__ __forceinline__ unsigned pk2(float a, float b) {
  __hip_bfloat162 h = __float22bfloat162_rn(float2{a, b});
  union { __hip_bfloat162 h; unsigned u; } x; x.h = h;
  return x.u;
}

__device__ __forceinline__ float blo(unsigned u) {
  union { unsigned u; float f; } x; x.u = u << 16; return x.f;
}
__device__ __forceinline__ float bhi(unsigned u) {
  union { unsigned u; float f; } x; x.u = u & 0xffff0000u; return x.f;
}

// XOR-swizzled ushort index into a [64][64] (128 B/row) LDS tile.
// byte_off within row ^= (row&7)<<4: spreads the 16B slot across 8 bank-groups.
// Conflict-free for: b128 staging writes, b128 frag reads (rows = c*16+l16,
// col = ks*64+quad*16), b64 P writes (col = c*32+quad*8), b128 P reads.
__device__ __forceinline__ int swz64(int row, int colbyte) {
  return row * 64 + ((colbyte ^ ((row & 7) << 4)) >> 1);
}

// Single fused cast: x (1M uint4) + Wq/Wk/Wv (-> wqkv) + Wo (-> wob).
__global__ __launch_bounds__(256) void cast_all(const float* __restrict__ x,
                                                const float* __restrict__ Wq,
                                                const float* __restrict__ Wk,
                                                const float* __restrict__ Wv,
                                                const float* __restrict__ Wo,
                                                ushort* __restrict__ xb,
                                                ushort* __restrict__ wqkv,
                                                ushort* __restrict__ wob) {
  int idx = blockIdx.x * 256 + threadIdx.x;  // 0 .. 2M-1 (uint4 units)
  const float* in;
  uint2* out;
  if (idx < (1 << 20)) {
    in = x; out = (uint2*)xb;
  } else {
    int j = idx - (1 << 20);
    int w = j >> 18;            // 0..3
    idx = j & 0x3FFFF;          // 256K uint4 per weight
    switch (w) {
      case 0: in = Wq; out = (uint2*)wqkv; break;
      case 1: in = Wk; out = (uint2*)(wqkv) + (1 << 18); break;
      case 2: in = Wv; out = (uint2*)(wqkv) + (2 << 18); break;
      default: in = Wo; out = (uint2*)wob; break;
    }
  }
  float4 v = ((const float4*)in)[idx];
  uint2 o; o.x = pk2(v.x, v.y); o.y = pk2(v.z, v.w);
  out[idx] = o;
}

// Fused QKV projection: A = xb (4096x1024 bf16), Bw = wqkv (3072x1024 bf16).
// 128x128 tile, BK=64 (16 K-iters).
// n<1024 -> Q (scaled), <2048 -> K, else -> V^T (packed b64 stores along t).
__global__ __launch_bounds__(256) void gemm_qkv(const ushort* __restrict__ A,
                                                const ushort* __restrict__ Bw,
                                                ushort* __restrict__ Qh,
                                                ushort* __restrict__ Kh,
                                                ushort* __restrict__ Vth,
                                                float qscale) {
  constexpr int K = 1024;
  const int bm = blockIdx.y * 128;
  const int bn = blockIdx.x * 128;
  const int tid = threadIdx.x;
  const int wave = tid >> 6;
  const int lane = tid & 63;
  const int l16 = lane & 15;
  const int quad = lane >> 4;

  __shared__ ushort As[128 * 64];   // 16 KB
  __shared__ ushort Bs[128 * 64];   // 16 KB

  const int wm = (wave & 1) * 64;
  const int wn = (wave >> 1) * 64;

  f32x4 acc[4][4];
#pragma unroll
  for (int r = 0; r < 4; ++r)
#pragma unroll
    for (int c = 0; c < 4; ++c) acc[r][c] = (f32x4){0.f, 0.f, 0.f, 0.f};

  const int srow = wave * 8 + (lane >> 3);
  const int scol = (lane & 7) * 8;

  for (int k0 = 0; k0 < K; k0 += 64) {
#pragma unroll
    for (int j = 0; j < 4; ++j) {
      async_cp16(A  + (size_t)(bm + j * 32 + srow) * K + k0 + scol, &As[(j * 32 + wave * 8) * 64]);
      async_cp16(Bw + (size_t)(bn + j * 32 + srow) * K + k0 + scol, &Bs[(j * 32 + wave * 8) * 64]);
    }
    __syncthreads();

    bf16x8 a[2][4], b[2][4];
#pragma unroll
    for (int ks = 0; ks < 2; ++ks)
#pragma unroll
      for (int r = 0; r < 4; ++r) {
        a[ks][r] = *(const bf16x8*)(&As[(wm + r * 16 + l16) * 64 + ks * 32 + quad * 8]);
        b[ks][r] = *(const bf16x8*)(&Bs[(wn + r * 16 + l16) * 64 + ks * 32 + quad * 8]);
      }
#pragma unroll
    for (int ks = 0; ks < 2; ++ks)
#pragma unroll
      for (int r = 0; r < 4; ++r)
#pragma unroll
        for (int c = 0; c < 4; ++c)
          acc[r][c] = __builtin_amdgcn_mfma_f32_16x16x32_bf16(a[ks][r], b[ks][c], acc[r][c], 0, 0, 0);
    __syncthreads();
  }

#pragma unroll
  for (int r = 0; r < 4; ++r) {
#pragma unroll
    for (int c = 0; c < 4; ++c) {
      int ncol = bn + wn + c * 16 + l16;   // 0..3071; w uniform per (block,wave)
      int w = ncol >> 10;
      int f = ncol & 1023;
      int h = f >> 6, d = f & 63;
      if (w == 2) {
        // V^T: 4 consecutive tokens per lane -> one b64 store
        int m0 = bm + wm + r * 16 + quad * 4;
        int b = m0 >> 11, t0 = m0 & 2047;
        uint2 pp;
        pp.x = pk2(acc[r][c][0], acc[r][c][1]);
        pp.y = pk2(acc[r][c][2], acc[r][c][3]);
        *(uint2*)(&Vth[((size_t)(b * 1024 + f) << 11) + t0]) = pp;
      } else {
#pragma unroll
        for (int rr = 0; rr < 4; ++rr) {
          float v = acc[r][c][rr];
          int m = bm + wm + r * 16 + quad * 4 + rr;
          int b = m >> 11, t = m & 2047;
          if (w == 0)
            Qh[((size_t)(b * 16 + h) * SEQ + t) * 64 + d] = f2b(v * qscale);
          else
            Kh[((size_t)(b * 16 + h) * SEQ + t) * 64 + d] = f2b(v);
        }
      }
    }
  }
}

// Output projection: A = ctx (4096x1024 bf16), Bw = wob, fp32 out.
// 64x128 tile, BK=64.
__global__ __launch_bounds__(256) void gemm_out(const ushort* __restrict__ A,
                                                const ushort* __restrict__ Bw,
                                                float* __restrict__ out) {
  constexpr int K = 1024;
  const int bm = blockIdx.y * 64;
  const int bn = blockIdx.x * 128;
  const int tid = threadIdx.x;
  const int wave = tid >> 6;
  const int lane = tid & 63;
  const int l16 = lane & 15;
  const int quad = lane >> 4;

  __shared__ ushort As[64 * 64];    //  8 KB
  __shared__ ushort Bs[128 * 64];   // 16 KB

  const int wm = (wave & 1) * 32;
  const int wn = (wave >> 1) * 64;

  f32x4 acc[2][4];
#pragma unroll
  for (int r = 0; r < 2; ++r)
#pragma unroll
    for (int c = 0; c < 4; ++c) acc[r][c] = (f32x4){0.f, 0.f, 0.f, 0.f};

  const int srow = wave * 8 + (lane >> 3);
  const int scol = (lane & 7) * 8;

  for (int k0 = 0; k0 < K; k0 += 64) {
#pragma unroll
    for (int j = 0; j < 2; ++j)
      async_cp16(A + (size_t)(bm + j * 32 + srow) * K + k0 + scol, &As[(j * 32 + wave * 8) * 64]);
#pragma unroll
    for (int j = 0; j < 4; ++j)
      async_cp16(Bw + (size_t)(bn + j * 32 + srow) * K + k0 + scol, &Bs[(j * 32 + wave * 8) * 64]);
    __syncthreads();

    bf16x8 a[2][2], b[2][4];
#pragma unroll
    for (int ks = 0; ks < 2; ++ks) {
#pragma unroll
      for (int r = 0; r < 2; ++r)
        a[ks][r] = *(const bf16x8*)(&As[(wm + r * 16 + l16) * 64 + ks * 32 + quad * 8]);
#pragma unroll
      for (int c = 0; c < 4; ++c)
        b[ks][c] = *(const bf16x8*)(&Bs[(wn + c * 16 + l16) * 64 + ks * 32 + quad * 8]);
    }
#pragma unroll
    for (int ks = 0; ks < 2; ++ks)
#pragma unroll
      for (int r = 0; r < 2; ++r)
#pragma unroll
        for (int c = 0; c < 4; ++c)
          acc[r][c] = __builtin_amdgcn_mfma_f32_16x16x32_bf16(a[ks][r], b[ks][c], acc[r][c], 0, 0, 0);
    __syncthreads();
  }

#pragma unroll
  for (int r = 0; r < 2; ++r)
#pragma unroll
    for (int c = 0; c < 4; ++c)
#pragma unroll
      for (int rr = 0; rr < 4; ++rr) {
        int m = bm + wm + r * 16 + quad * 4 + rr;
        int n = bn + wn + c * 16 + l16;
        out[(size_t)m * D_MODEL + n] = acc[r][c][rr];
      }
}

// Flash attention, R13: fix R12's scratch-spill regression.
// R12 post-mortem: launch_bounds(256,4) forced a 128-reg unified budget;
// live set (~155) spilled ~8 dwords/thread/iter in the K-loop -> +124 MB
// HBM writes (WRITE_SIZE 17->140 MB), VGPR_Count capped at 64.
// R13: (a) c-outer restructure so ka/vb live one-at-a-time (live set ~100
// arch + 40 acc), (b) launch_bounds(256,3): ~170-reg budget, zero spills,
// 12 waves/CU (vs 8 in R11); (c) O partial stores staged through LDS
// (reusing Kt/Vt post-loop) and written as full-line coalesced uint4.
// Grid keeps XCD affinity: id = qb*64 + stream; id%8 = stream%8 so all 16
// q-blocks of one K/V stream share an XCD (8 streams * 256 KB = 2 MB < L2).
__global__ __launch_bounds__(256, 3) void attn_kernel(const ushort* __restrict__ Qh,
                                                      const ushort* __restrict__ Kh,
                                                      const ushort* __restrict__ Vth,
                                                      ushort* __restrict__ O1,
                                                      ushort* __restrict__ O2,
                                                      float* __restrict__ l1,
                                                      float* __restrict__ l2) {
  const int id = blockIdx.x;
  const int stream = id & 63;       // bh*2 + half
  const int qb = id >> 6;           // 0..15
  const int bh = stream >> 1;
  const int half = stream & 1;
  const int q0 = qb * 128;
  ushort* __restrict__ Op = half ? O2 : O1;
  float* __restrict__ lp = half ? l2 : l1;

  const int tid = threadIdx.x;
  const int wave = tid >> 6;
  const int lane = tid & 63;
  const int l16 = lane & 15;
  const int quad = lane >> 4;

  // 16 KB K/V staging (swizzled) reused as the 16 KB O-store tile post-loop.
  __shared__ ushort KV[2 * 64 * 64];
  __shared__ ushort Pt[2][64 * 64];  // 16 KB [q(wave*16+l16)][key], swizzled
  ushort* const Kt = KV;             // 8 KB [key][d]
  ushort* const Vt = KV + 64 * 64;   // 8 KB [d][key]

  bf16x8 qf[2][2];
#pragma unroll
  for (int g = 0; g < 2; ++g) {
    const ushort* qp = Qh + ((size_t)bh * SEQ + q0 + wave * 32 + g * 16 + l16) * 64 + quad * 8;
    qf[g][0] = *(const bf16x8*)(qp);
    qf[g][1] = *(const bf16x8*)(qp + 32);
  }

  bf16x8 ones;
#pragma unroll
  for (int j = 0; j < 8; ++j) ones[j] = (short)0x3F80;  // bf16 1.0

  f32x4 o[2][4];
  f32x4 lacc[2];
#pragma unroll
  for (int g = 0; g < 2; ++g) {
    lacc[g] = (f32x4){0.f, 0.f, 0.f, 0.f};
#pragma unroll
    for (int c = 0; c < 4; ++c) o[g][c] = (f32x4){0.f, 0.f, 0.f, 0.f};
  }

  const int srow = tid >> 3;        // 0..31
  const int scolb = (tid & 7) * 16; // staging col in BYTES
  const ushort* kbase = Kh + ((size_t)bh * SEQ + half * 1024) * 64;
  const ushort* vbase = Vth + (size_t)bh * 64 * SEQ + half * 1024;

  uint4 kreg[2], vreg[2];
#pragma unroll
  for (int i = 0; i < 2; ++i) {
    kreg[i] = *(const uint4*)(kbase + (size_t)(i * 32 + srow) * 64 + (scolb >> 1));
    vreg[i] = *(const uint4*)(vbase + (size_t)(i * 32 + srow) * SEQ + (scolb >> 1));
  }

  constexpr int NIT = 1024 / 64;  // 16
  for (int kt = 0; kt < NIT; ++kt) {
    __syncthreads();  // prior-iter LDS reads complete
#pragma unroll
    for (int i = 0; i < 2; ++i) {
      *(uint4*)(&Kt[swz64(i * 32 + srow, scolb)]) = kreg[i];
      *(uint4*)(&Vt[swz64(i * 32 + srow, scolb)]) = vreg[i];
    }
    __syncthreads();  // staging visible
    if (kt + 1 < NIT) {
      // issued after the barrier so its vmcnt drain doesn't eat the prefetch
#pragma unroll
      for (int i = 0; i < 2; ++i) {
        kreg[i] = *(const uint4*)(kbase + (size_t)((kt + 1) * 64 + i * 32 + srow) * 64 + (scolb >> 1));
        vreg[i] = *(const uint4*)(vbase + (size_t)(i * 32 + srow) * SEQ + (kt + 1) * 64 + (scolb >> 1));
      }
    }

    const int prow = wave * 16 + l16;
    // QK^T, c-outer: one ka fragment live at a time (register pressure).
#pragma unroll
    for (int c = 0; c < 4; ++c) {
      bf16x8 ka0 = *(const bf16x8*)(&Kt[swz64(c * 16 + l16, quad * 16)]);
      bf16x8 ka1 = *(const bf16x8*)(&Kt[swz64(c * 16 + l16, 64 + quad * 16)]);
#pragma unroll
      for (int g = 0; g < 2; ++g) {
        f32x4 z = (f32x4){0.f, 0.f, 0.f, 0.f};
        z = __builtin_amdgcn_mfma_f32_16x16x32_bf16(ka0, qf[g][0], z, 0, 0, 0);
        z = __builtin_amdgcn_mfma_f32_16x16x32_bf16(ka1, qf[g][1], z, 0, 0, 0);
        uint2 pp;
        pp.x = pk2(__builtin_amdgcn_exp2f(z[0]), __builtin_amdgcn_exp2f(z[1]));
        pp.y = pk2(__builtin_amdgcn_exp2f(z[2]), __builtin_amdgcn_exp2f(z[3]));
        *(uint2*)(&Pt[g][swz64(prow, c * 32 + quad * 8)]) = pp;
      }
    }

    // P frags (same-wave rows; in-order LDS pipe, fine-grained lgkmcnt)
    bf16x8 pf[2][2];
#pragma unroll
    for (int g = 0; g < 2; ++g) {
      pf[g][0] = *(const bf16x8*)(&Pt[g][swz64(prow, quad * 16)]);
      pf[g][1] = *(const bf16x8*)(&Pt[g][swz64(prow, 64 + quad * 16)]);
      // l += P . 1  (C-layout, same rows as O)
      lacc[g] = __builtin_amdgcn_mfma_f32_16x16x32_bf16(pf[g][0], ones, lacc[g], 0, 0, 0);
      lacc[g] = __builtin_amdgcn_mfma_f32_16x16x32_bf16(pf[g][1], ones, lacc[g], 0, 0, 0);
    }
    // O += P . V, c-outer: one vb fragment live at a time.
#pragma unroll
    for (int c = 0; c < 4; ++c) {
      bf16x8 vb0 = *(const bf16x8*)(&Vt[swz64(c * 16 + l16, quad * 16)]);
      bf16x8 vb1 = *(const bf16x8*)(&Vt[swz64(c * 16 + l16, 64 + quad * 16)]);
#pragma unroll
      for (int g = 0; g < 2; ++g) {
        o[g][c] = __builtin_amdgcn_mfma_f32_16x16x32_bf16(pf[g][0], vb0, o[g][c], 0, 0, 0);
        o[g][c] = __builtin_amdgcn_mfma_f32_16x16x32_bf16(pf[g][1], vb1, o[g][c], 0, 0, 0);
      }
    }
  }

  // O-store: stage the 128x64 bf16 tile into LDS (reuse KV; one-time cost),
  // then write full 128B lines with coalesced uint4 (4 KB/instr).
  __syncthreads();  // all waves done reading Kt/Vt
#pragma unroll
  for (int g = 0; g < 2; ++g) {
#pragma unroll
    for (int r = 0; r < 4; ++r) {
      int row = wave * 32 + g * 16 + quad * 4 + r;
#pragma unroll
      for (int c = 0; c < 4; ++c)
        KV[row * 64 + c * 16 + l16] = f2b(o[g][c][r]);
    }
    if (l16 == 0) {
#pragma unroll
      for (int r = 0; r < 4; ++r) {
        int t = q0 + wave * 32 + g * 16 + quad * 4 + r;
        lp[(size_t)bh * SEQ + t] = lacc[g][r];
      }
    }
  }
  __syncthreads();  // O tile visible
  {
    uint4* dst = (uint4*)(Op + ((size_t)bh * SEQ + q0) * 64);
    const uint4* src = (const uint4*)KV;
#pragma unroll
    for (int i = 0; i < 4; ++i)
      dst[i * 256 + tid] = src[i * 256 + tid];
  }
}

// ctx = (O1 + O2) / (l1 + l2), routed to (B, T, D_MODEL) bf16
__global__ __launch_bounds__(256) void recombine(const ushort* __restrict__ O1,
                                                 const ushort* __restrict__ O2,
                                                 const float* __restrict__ l1,
                                                 const float* __restrict__ l2,
                                                 ushort* __restrict__ ctx) {
  int idx = blockIdx.x * 256 + threadIdx.x;   // over (BH*T*64)/8 uint4 chunks
  int row = idx >> 3;                         // bh*SEQ + t
  int d8 = idx & 7;
  uint4 a = ((const uint4*)O1)[idx];
  uint4 b = ((const uint4*)O2)[idx];
  float linv = 1.f / (l1[row] + l2[row]);
  uint4 res;
  unsigned* ap = (unsigned*)&a;
  unsigned* bp = (unsigned*)&b;
  unsigned* rp = (unsigned*)&res;
#pragma unroll
  for (int i = 0; i < 4; ++i) {
    float lo = (blo(ap[i]) + blo(bp[i])) * linv;
    float hi = (bhi(ap[i]) + bhi(bp[i])) * linv;
    rp[i] = pk2(lo, hi);
  }
  int bh = row >> 11, t = row & 2047;
  int bb = bh >> 4, h = bh & 15;
  ((uint4*)ctx)[(size_t)(bb * SEQ + t) * 128 + h * 8 + d8] = res;
}

extern "C" void kernel_launch(void* const* d_in, const int* in_sizes, int n_in,
                              void* d_out, int out_size, void* d_ws, size_t ws_size,
                              hipStream_t stream) {
  const float* x  = (const float*)d_in[0];
  const float* Wq = (const float*)d_in[1];
  const float* Wk = (const float*)d_in[2];
  const float* Wv = (const float*)d_in[3];
  const float* Wo = (const float*)d_in[4];
  float* out = (float*)d_out;

  char* ws = (char*)d_ws;
  const size_t MB = 1 << 20;
  ushort* xb   = (ushort*)(ws);             // 8 MB (dead after gemm_qkv -> O2)
  ushort* wqkv = (ushort*)(ws +  8 * MB);   // 6 MB (dead after gemm_qkv -> l1/l2)
  ushort* wob  = (ushort*)(ws + 14 * MB);   // 2 MB (live until gemm_out)
  ushort* Qh   = (ushort*)(ws + 16 * MB);   // 8 MB (BH,T,64)
  ushort* Kh   = (ushort*)(ws + 24 * MB);   // 8 MB (BH,T,64)
  ushort* Vth  = (ushort*)(ws + 32 * MB);   // 8 MB (BH,64,T)
  ushort* ctx  = (ushort*)(ws + 40 * MB);   // 8 MB (B,T,D)

  // split-K partials (regions dead during attn):
  ushort* O1 = (ushort*)d_out;              // 8 MB of the 16 MB output buffer
  ushort* O2 = xb;                          // xb region, dead after gemm_qkv
  float*  l1 = (float*)wqkv;                // 256 KB
  float*  l2 = (float*)(ws + 8 * MB + 256 * 1024);

  cast_all<<<8192, 256, 0, stream>>>(x, Wq, Wk, Wv, Wo, xb, wqkv, wob);

  const float qscale = 0.125f * 1.44269504089f;  // SCALE * log2(e)
  gemm_qkv<<<dim3(3072 / 128, 4096 / 128), 256, 0, stream>>>(xb, wqkv, Qh, Kh, Vth, qscale);

  // 1D grid, 1024 blocks: id = qb*64 + (bh*2+half) -> id%8 fixed per stream
  attn_kernel<<<(SEQ / 128) * BATCH * N_HEADS * 2, 256, 0, stream>>>(
      Qh, Kh, Vth, O1, O2, l1, l2);

  recombine<<<(BATCH * N_HEADS * SEQ * 64 / 8) / 256, 256, 0, stream>>>(O1, O2, l1, l2, ctx);

  gemm_out<<<dim3(1024 / 128, 4096 / 64), 256, 0, stream>>>(ctx, wob, out);
}

// Round 3
// 206.482 us; speedup vs baseline: 1.1704x; 1.1704x over previous
//
#include <hip/hip_runtime.h>
#include <hip/hip_bf16.h>

#define D_MODEL 1024
#define N_HEADS 16
#define HEAD_DIM 64
#define SEQ 2048
#define BATCH 2

typedef __attribute__((ext_vector_type(8))) short bf16x8;
typedef __attribute__((ext_vector_type(4))) float f32x4;

typedef __attribute__((address_space(3))) unsigned lds_uint;
typedef __attribute__((address_space(1))) const unsigned global_cuint;

__device__ __forceinline__ void async_cp16(const ushort* g, ushort* l) {
  __builtin_amdgcn_global_load_lds((global_cuint*)g, (lds_uint*)l, 16, 0, 0);
}

__device__ __forceinline__ ushort f2b(float f) {
  union { float f; unsigned u; } x; x.f = f;
  unsigned r = x.u + 0x7fffu + ((x.u >> 16) & 1u);
  return (ushort)(r >> 16);
}

// packed f32x2 -> bf16x2; low word = a
__device__ __forceinline__ unsigned pk2(float a, float b) {
  __hip_bfloat162 h = __float22bfloat162_rn(float2{a, b});
  union { __hip_bfloat162 h; unsigned u; } x; x.h = h;
  return x.u;
}

__device__ __forceinline__ float blo(unsigned u) {
  union { unsigned u; float f; } x; x.u = u << 16; return x.f;
}
__device__ __forceinline__ float bhi(unsigned u) {
  union { unsigned u; float f; } x; x.u = u & 0xffff0000u; return x.f;
}

// XOR-swizzled ushort index into a [64][64] (128 B/row) LDS tile.
// byte_off within row ^= (row&7)<<4: spreads the 16B slot across 8 bank-groups.
// Conflict-free for: b128 staging writes, b128 frag reads (rows = c*16+l16,
// col = ks*64+quad*16), b64 P writes (col = c*32+quad*8), b128 P reads.
__device__ __forceinline__ int swz64(int row, int colbyte) {
  return row * 64 + ((colbyte ^ ((row & 7) << 4)) >> 1);
}

// Single fused cast: x (1M uint4) + Wq/Wk/Wv (-> wqkv) + Wo (-> wob).
__global__ __launch_bounds__(256) void cast_all(const float* __restrict__ x,
                                                const float* __restrict__ Wq,
                                                const float* __restrict__ Wk,
                                                const float* __restrict__ Wv,
                                                const float* __restrict__ Wo,
                                                ushort* __restrict__ xb,
                                                ushort* __restrict__ wqkv,
                                                ushort* __restrict__ wob) {
  int idx = blockIdx.x * 256 + threadIdx.x;  // 0 .. 2M-1 (uint4 units)
  const float* in;
  uint2* out;
  if (idx < (1 << 20)) {
    in = x; out = (uint2*)xb;
  } else {
    int j = idx - (1 << 20);
    int w = j >> 18;            // 0..3
    idx = j & 0x3FFFF;          // 256K uint4 per weight
    switch (w) {
      case 0: in = Wq; out = (uint2*)wqkv; break;
      case 1: in = Wk; out = (uint2*)(wqkv) + (1 << 18); break;
      case 2: in = Wv; out = (uint2*)(wqkv) + (2 << 18); break;
      default: in = Wo; out = (uint2*)wob; break;
    }
  }
  float4 v = ((const float4*)in)[idx];
  uint2 o; o.x = pk2(v.x, v.y); o.y = pk2(v.z, v.w);
  out[idx] = o;
}

// Fused QKV projection: A = xb (4096x1024 bf16), Bw = wqkv (3072x1024 bf16).
// 128x128 tile, BK=64 (16 K-iters).
// n<1024 -> Q (scaled), <2048 -> K, else -> V^T (packed b64 stores along t).
__global__ __launch_bounds__(256) void gemm_qkv(const ushort* __restrict__ A,
                                                const ushort* __restrict__ Bw,
                                                ushort* __restrict__ Qh,
                                                ushort* __restrict__ Kh,
                                                ushort* __restrict__ Vth,
                                                float qscale) {
  constexpr int K = 1024;
  const int bm = blockIdx.y * 128;
  const int bn = blockIdx.x * 128;
  const int tid = threadIdx.x;
  const int wave = tid >> 6;
  const int lane = tid & 63;
  const int l16 = lane & 15;
  const int quad = lane >> 4;

  __shared__ ushort As[128 * 64];   // 16 KB
  __shared__ ushort Bs[128 * 64];   // 16 KB

  const int wm = (wave & 1) * 64;
  const int wn = (wave >> 1) * 64;

  f32x4 acc[4][4];
#pragma unroll
  for (int r = 0; r < 4; ++r)
#pragma unroll
    for (int c = 0; c < 4; ++c) acc[r][c] = (f32x4){0.f, 0.f, 0.f, 0.f};

  const int srow = wave * 8 + (lane >> 3);
  const int scol = (lane & 7) * 8;

  for (int k0 = 0; k0 < K; k0 += 64) {
#pragma unroll
    for (int j = 0; j < 4; ++j) {
      async_cp16(A  + (size_t)(bm + j * 32 + srow) * K + k0 + scol, &As[(j * 32 + wave * 8) * 64]);
      async_cp16(Bw + (size_t)(bn + j * 32 + srow) * K + k0 + scol, &Bs[(j * 32 + wave * 8) * 64]);
    }
    __syncthreads();

    bf16x8 a[2][4], b[2][4];
#pragma unroll
    for (int ks = 0; ks < 2; ++ks)
#pragma unroll
      for (int r = 0; r < 4; ++r) {
        a[ks][r] = *(const bf16x8*)(&As[(wm + r * 16 + l16) * 64 + ks * 32 + quad * 8]);
        b[ks][r] = *(const bf16x8*)(&Bs[(wn + r * 16 + l16) * 64 + ks * 32 + quad * 8]);
      }
#pragma unroll
    for (int ks = 0; ks < 2; ++ks)
#pragma unroll
      for (int r = 0; r < 4; ++r)
#pragma unroll
        for (int c = 0; c < 4; ++c)
          acc[r][c] = __builtin_amdgcn_mfma_f32_16x16x32_bf16(a[ks][r], b[ks][c], acc[r][c], 0, 0, 0);
    __syncthreads();
  }

#pragma unroll
  for (int r = 0; r < 4; ++r) {
#pragma unroll
    for (int c = 0; c < 4; ++c) {
      int ncol = bn + wn + c * 16 + l16;   // 0..3071; w uniform per (block,wave)
      int w = ncol >> 10;
      int f = ncol & 1023;
      int h = f >> 6, d = f & 63;
      if (w == 2) {
        // V^T: 4 consecutive tokens per lane -> one b64 store
        int m0 = bm + wm + r * 16 + quad * 4;
        int b = m0 >> 11, t0 = m0 & 2047;
        uint2 pp;
        pp.x = pk2(acc[r][c][0], acc[r][c][1]);
        pp.y = pk2(acc[r][c][2], acc[r][c][3]);
        *(uint2*)(&Vth[((size_t)(b * 1024 + f) << 11) + t0]) = pp;
      } else {
#pragma unroll
        for (int rr = 0; rr < 4; ++rr) {
          float v = acc[r][c][rr];
          int m = bm + wm + r * 16 + quad * 4 + rr;
          int b = m >> 11, t = m & 2047;
          if (w == 0)
            Qh[((size_t)(b * 16 + h) * SEQ + t) * 64 + d] = f2b(v * qscale);
          else
            Kh[((size_t)(b * 16 + h) * SEQ + t) * 64 + d] = f2b(v);
        }
      }
    }
  }
}

// Output projection: A = ctx (4096x1024 bf16), Bw = wob, fp32 out.
// 64x128 tile, BK=64.
__global__ __launch_bounds__(256) void gemm_out(const ushort* __restrict__ A,
                                                const ushort* __restrict__ Bw,
                                                float* __restrict__ out) {
  constexpr int K = 1024;
  const int bm = blockIdx.y * 64;
  const int bn = blockIdx.x * 128;
  const int tid = threadIdx.x;
  const int wave = tid >> 6;
  const int lane = tid & 63;
  const int l16 = lane & 15;
  const int quad = lane >> 4;

  __shared__ ushort As[64 * 64];    //  8 KB
  __shared__ ushort Bs[128 * 64];   // 16 KB

  const int wm = (wave & 1) * 32;
  const int wn = (wave >> 1) * 64;

  f32x4 acc[2][4];
#pragma unroll
  for (int r = 0; r < 2; ++r)
#pragma unroll
    for (int c = 0; c < 4; ++c) acc[r][c] = (f32x4){0.f, 0.f, 0.f, 0.f};

  const int srow = wave * 8 + (lane >> 3);
  const int scol = (lane & 7) * 8;

  for (int k0 = 0; k0 < K; k0 += 64) {
#pragma unroll
    for (int j = 0; j < 2; ++j)
      async_cp16(A + (size_t)(bm + j * 32 + srow) * K + k0 + scol, &As[(j * 32 + wave * 8) * 64]);
#pragma unroll
    for (int j = 0; j < 4; ++j)
      async_cp16(Bw + (size_t)(bn + j * 32 + srow) * K + k0 + scol, &Bs[(j * 32 + wave * 8) * 64]);
    __syncthreads();

    bf16x8 a[2][2], b[2][4];
#pragma unroll
    for (int ks = 0; ks < 2; ++ks) {
#pragma unroll
      for (int r = 0; r < 2; ++r)
        a[ks][r] = *(const bf16x8*)(&As[(wm + r * 16 + l16) * 64 + ks * 32 + quad * 8]);
#pragma unroll
      for (int c = 0; c < 4; ++c)
        b[ks][c] = *(const bf16x8*)(&Bs[(wn + c * 16 + l16) * 64 + ks * 32 + quad * 8]);
    }
#pragma unroll
    for (int ks = 0; ks < 2; ++ks)
#pragma unroll
      for (int r = 0; r < 2; ++r)
#pragma unroll
        for (int c = 0; c < 4; ++c)
          acc[r][c] = __builtin_amdgcn_mfma_f32_16x16x32_bf16(a[ks][r], b[ks][c], acc[r][c], 0, 0, 0);
    __syncthreads();
  }

#pragma unroll
  for (int r = 0; r < 2; ++r)
#pragma unroll
    for (int c = 0; c < 4; ++c)
#pragma unroll
      for (int rr = 0; rr < 4; ++rr) {
        int m = bm + wm + r * 16 + quad * 4 + rr;
        int n = bn + wn + c * 16 + l16;
        out[(size_t)m * D_MODEL + n] = acc[r][c][rr];
      }
}

// Flash attention, R14: remove the register-staging pipeline entirely.
// R12/R13 post-mortem: (256,3)==(256,4) (HW reg quantum 64/128/256 -> only
// 8/4/2 waves/SIMD); true demand ~150 > 128 -> spills (~123 MB scratch
// writes). R14 shrinks REAL demand instead of capping:
//  - K/V staged with global_load_lds (no kreg/vreg, no hoistable load regs),
//    double-buffered in LDS (2x16KB). Swizzled layout achieved by
//    pre-swizzling the GLOBAL source chunk index (XOR involution; stays
//    coalesced within 128B rows), LDS dest stays lane-linear.
//  - ONE __syncthreads per iter: its vmcnt(0) drain IS the wait for the
//    prefetched tile; prefetch for t+1 issued right after the barrier.
//  - l computed as scalar VALU sum of exp2 values (each lane owns 16 keys of
//    one query row in S^T layout); cross-quad reduce via 2 shfl_xor at end.
//    Drops the ones-operand l-MFMAs (64/block), lacc 8->2 regs.
//  - single 8 KB Pt: g-outer => g0 P-reads precede g1 P-writes in the
//    same-wave in-order LDS pipe. LDS total 40 KB.
// launch_bounds(256,2): 256-reg budget -> guaranteed no spills; if natural
// allocation lands <=128 the HW gives 4 waves/SIMD automatically.
__global__ __launch_bounds__(256, 2) void attn_kernel(const ushort* __restrict__ Qh,
                                                      const ushort* __restrict__ Kh,
                                                      const ushort* __restrict__ Vth,
                                                      ushort* __restrict__ O1,
                                                      ushort* __restrict__ O2,
                                                      float* __restrict__ l1,
                                                      float* __restrict__ l2) {
  const int id = blockIdx.x;
  const int stream = id & 63;       // bh*2 + half
  const int qb = id >> 6;           // 0..15
  const int bh = stream >> 1;
  const int half = stream & 1;
  const int q0 = qb * 128;
  ushort* __restrict__ Op = half ? O2 : O1;
  float* __restrict__ lp = half ? l2 : l1;

  const int tid = threadIdx.x;
  const int wave = tid >> 6;
  const int lane = tid & 63;
  const int l16 = lane & 15;
  const int quad = lane >> 4;

  __shared__ ushort KVbuf[2][2][64 * 64];  // 32 KB: [buf][0=K,1=V^T], swizzled
  __shared__ ushort Pt[64 * 64];           // 8 KB  [q(wave*16+l16)][key], swizzled

  bf16x8 qf[2][2];
#pragma unroll
  for (int g = 0; g < 2; ++g) {
    const ushort* qp = Qh + ((size_t)bh * SEQ + q0 + wave * 32 + g * 16 + l16) * 64 + quad * 8;
    qf[g][0] = *(const bf16x8*)(qp);
    qf[g][1] = *(const bf16x8*)(qp + 32);
  }

  f32x4 o[2][4];
  float lacc[2] = {0.f, 0.f};
#pragma unroll
  for (int g = 0; g < 2; ++g)
#pragma unroll
    for (int c = 0; c < 4; ++c) o[g][c] = (f32x4){0.f, 0.f, 0.f, 0.f};

  // async staging geometry: each wave fills chunks {2w, 2w+1} (8 rows each)
  // of the 64-row tile. Lane l covers row chunk*8 + (l>>3), 16B slot (l&7).
  // Global source column is pre-swizzled: slot_src = (l&7) ^ (l>>3), so the
  // lane-linear LDS write leaves data at the swz64 position.
  const int chunk = wave * 2;
  const int r8 = lane >> 3;
  const int csw = (((lane & 7) ^ r8) << 3);   // ushort offset within 64
  const ushort* kbase = Kh + ((size_t)bh * SEQ + half * 1024) * 64;
  const ushort* vbase = Vth + (size_t)bh * 64 * SEQ + half * 1024;
  const ushort* ksrc = kbase + (size_t)(chunk * 8 + r8) * 64 + csw;   // +kt*4096
  const ushort* vsrc = vbase + (size_t)(chunk * 8 + r8) * SEQ + csw;  // +kt*64

  // prologue: tile 0 -> buf 0
  async_cp16(ksrc,           &KVbuf[0][0][chunk * 512]);
  async_cp16(ksrc + 8 * 64,  &KVbuf[0][0][(chunk + 1) * 512]);
  async_cp16(vsrc,           &KVbuf[0][1][chunk * 512]);
  async_cp16(vsrc + 8 * SEQ, &KVbuf[0][1][(chunk + 1) * 512]);

  constexpr int NIT = 1024 / 64;  // 16
  for (int kt = 0; kt < NIT; ++kt) {
    __syncthreads();  // drains vmcnt: tile kt landed; prior reads of buf^1 done
    const int buf = kt & 1;
    if (kt + 1 < NIT) {
      const ushort* ks = ksrc + (size_t)(kt + 1) * 64 * 64;
      const ushort* vs = vsrc + (kt + 1) * 64;
      async_cp16(ks,           &KVbuf[buf ^ 1][0][chunk * 512]);
      async_cp16(ks + 8 * 64,  &KVbuf[buf ^ 1][0][(chunk + 1) * 512]);
      async_cp16(vs,           &KVbuf[buf ^ 1][1][chunk * 512]);
      async_cp16(vs + 8 * SEQ, &KVbuf[buf ^ 1][1][(chunk + 1) * 512]);
    }
    const ushort* Kt = KVbuf[buf][0];
    const ushort* Vt = KVbuf[buf][1];
    const int prow = wave * 16 + l16;

    // QK^T + exp2 + pack, g-outer (single Pt buffer; same-wave in-order LDS
    // pipe orders g0 reads before g1 writes).
    bf16x8 pf[2][2];
#pragma unroll
    for (int g = 0; g < 2; ++g) {
#pragma unroll
      for (int c = 0; c < 4; ++c) {
        bf16x8 ka0 = *(const bf16x8*)(&Kt[swz64(c * 16 + l16, quad * 16)]);
        bf16x8 ka1 = *(const bf16x8*)(&Kt[swz64(c * 16 + l16, 64 + quad * 16)]);
        f32x4 z = (f32x4){0.f, 0.f, 0.f, 0.f};
        z = __builtin_amdgcn_mfma_f32_16x16x32_bf16(ka0, qf[g][0], z, 0, 0, 0);
        z = __builtin_amdgcn_mfma_f32_16x16x32_bf16(ka1, qf[g][1], z, 0, 0, 0);
        float e0 = __builtin_amdgcn_exp2f(z[0]);
        float e1 = __builtin_amdgcn_exp2f(z[1]);
        float e2 = __builtin_amdgcn_exp2f(z[2]);
        float e3 = __builtin_amdgcn_exp2f(z[3]);
        lacc[g] += (e0 + e1) + (e2 + e3);
        uint2 pp;
        pp.x = pk2(e0, e1);
        pp.y = pk2(e2, e3);
        *(uint2*)(&Pt[swz64(prow, c * 32 + quad * 8)]) = pp;
      }
      pf[g][0] = *(const bf16x8*)(&Pt[swz64(prow, quad * 16)]);
      pf[g][1] = *(const bf16x8*)(&Pt[swz64(prow, 64 + quad * 16)]);
    }

    // O += P . V
#pragma unroll
    for (int c = 0; c < 4; ++c) {
      bf16x8 vb0 = *(const bf16x8*)(&Vt[swz64(c * 16 + l16, quad * 16)]);
      bf16x8 vb1 = *(const bf16x8*)(&Vt[swz64(c * 16 + l16, 64 + quad * 16)]);
#pragma unroll
      for (int g = 0; g < 2; ++g) {
        o[g][c] = __builtin_amdgcn_mfma_f32_16x16x32_bf16(pf[g][0], vb0, o[g][c], 0, 0, 0);
        o[g][c] = __builtin_amdgcn_mfma_f32_16x16x32_bf16(pf[g][1], vb1, o[g][c], 0, 0, 0);
      }
    }
  }

  // l: cross-quad reduce (each lane has the partial over its 16 keys/iter).
#pragma unroll
  for (int g = 0; g < 2; ++g) {
    lacc[g] += __shfl_xor(lacc[g], 16, 64);
    lacc[g] += __shfl_xor(lacc[g], 32, 64);
    if (quad == 0)
      lp[(size_t)bh * SEQ + q0 + wave * 32 + g * 16 + l16] = lacc[g];
  }

  // O-store: stage the 128x64 bf16 tile into LDS (reuse KVbuf), then write
  // full 128B lines with coalesced uint4 (4 KB/instr).
  __syncthreads();  // all waves done with K/V LDS
  ushort* Ob = &KVbuf[0][0][0];  // 16 KB region
#pragma unroll
  for (int g = 0; g < 2; ++g)
#pragma unroll
    for (int r = 0; r < 4; ++r) {
      int row = wave * 32 + g * 16 + quad * 4 + r;
#pragma unroll
      for (int c = 0; c < 4; ++c)
        Ob[row * 64 + c * 16 + l16] = f2b(o[g][c][r]);
    }
  __syncthreads();  // O tile visible
  {
    uint4* dst = (uint4*)(Op + ((size_t)bh * SEQ + q0) * 64);
    const uint4* src = (const uint4*)Ob;
#pragma unroll
    for (int i = 0; i < 4; ++i)
      dst[i * 256 + tid] = src[i * 256 + tid];
  }
}

// ctx = (O1 + O2) / (l1 + l2), routed to (B, T, D_MODEL) bf16
__global__ __launch_bounds__(256) void recombine(const ushort* __restrict__ O1,
                                                 const ushort* __restrict__ O2,
                                                 const float* __restrict__ l1,
                                                 const float* __restrict__ l2,
                                                 ushort* __restrict__ ctx) {
  int idx = blockIdx.x * 256 + threadIdx.x;   // over (BH*T*64)/8 uint4 chunks
  int row = idx >> 3;                         // bh*SEQ + t
  int d8 = idx & 7;
  uint4 a = ((const uint4*)O1)[idx];
  uint4 b = ((const uint4*)O2)[idx];
  float linv = 1.f / (l1[row] + l2[row]);
  uint4 res;
  unsigned* ap = (unsigned*)&a;
  unsigned* bp = (unsigned*)&b;
  unsigned* rp = (unsigned*)&res;
#pragma unroll
  for (int i = 0; i < 4; ++i) {
    float lo = (blo(ap[i]) + blo(bp[i])) * linv;
    float hi = (bhi(ap[i]) + bhi(bp[i])) * linv;
    rp[i] = pk2(lo, hi);
  }
  int bh = row >> 11, t = row & 2047;
  int bb = bh >> 4, h = bh & 15;
  ((uint4*)ctx)[(size_t)(bb * SEQ + t) * 128 + h * 8 + d8] = res;
}

extern "C" void kernel_launch(void* const* d_in, const int* in_sizes, int n_in,
                              void* d_out, int out_size, void* d_ws, size_t ws_size,
                              hipStream_t stream) {
  const float* x  = (const float*)d_in[0];
  const float* Wq = (const float*)d_in[1];
  const float* Wk = (const float*)d_in[2];
  const float* Wv = (const float*)d_in[3];
  const float* Wo = (const float*)d_in[4];
  float* out = (float*)d_out;

  char* ws = (char*)d_ws;
  const size_t MB = 1 << 20;
  ushort* xb   = (ushort*)(ws);             // 8 MB (dead after gemm_qkv -> O2)
  ushort* wqkv = (ushort*)(ws +  8 * MB);   // 6 MB (dead after gemm_qkv -> l1/l2)
  ushort* wob  = (ushort*)(ws + 14 * MB);   // 2 MB (live until gemm_out)
  ushort* Qh   = (ushort*)(ws + 16 * MB);   // 8 MB (BH,T,64)
  ushort* Kh   = (ushort*)(ws + 24 * MB);   // 8 MB (BH,T,64)
  ushort* Vth  = (ushort*)(ws + 32 * MB);   // 8 MB (BH,64,T)
  ushort* ctx  = (ushort*)(ws + 40 * MB);   // 8 MB (B,T,D)

  // split-K partials (regions dead during attn):
  ushort* O1 = (ushort*)d_out;              // 8 MB of the 16 MB output buffer
  ushort* O2 = xb;                          // xb region, dead after gemm_qkv
  float*  l1 = (float*)wqkv;                // 256 KB
  float*  l2 = (float*)(ws + 8 * MB + 256 * 1024);

  cast_all<<<8192, 256, 0, stream>>>(x, Wq, Wk, Wv, Wo, xb, wqkv, wob);

  const float qscale = 0.125f * 1.44269504089f;  // SCALE * log2(e)
  gemm_qkv<<<dim3(3072 / 128, 4096 / 128), 256, 0, stream>>>(xb, wqkv, Qh, Kh, Vth, qscale);

  // 1D grid, 1024 blocks: id = qb*64 + (bh*2+half) -> id%8 fixed per stream
  attn_kernel<<<(SEQ / 128) * BATCH * N_HEADS * 2, 256, 0, stream>>>(
      Qh, Kh, Vth, O1, O2, l1, l2);

  recombine<<<(BATCH * N_HEADS * SEQ * 64 / 8) / 256, 256, 0, stream>>>(O1, O2, l1, l2, ctx);

  gemm_out<<<dim3(1024 / 128, 4096 / 64), 256, 0, stream>>>(ctx, wob, out);
}

// Round 4
// 198.887 us; speedup vs baseline: 1.2151x; 1.0382x over previous
//
#include <hip/hip_runtime.h>
#include <hip/hip_bf16.h>

#define D_MODEL 1024
#define N_HEADS 16
#define HEAD_DIM 64
#define SEQ 2048
#define BATCH 2

typedef __attribute__((ext_vector_type(8))) short bf16x8;
typedef __attribute__((ext_vector_type(4))) float f32x4;

typedef __attribute__((address_space(3))) unsigned lds_uint;
typedef __attribute__((address_space(1))) const unsigned global_cuint;

__device__ __forceinline__ void async_cp16(const ushort* g, ushort* l) {
  __builtin_amdgcn_global_load_lds((global_cuint*)g, (lds_uint*)l, 16, 0, 0);
}

__device__ __forceinline__ ushort f2b(float f) {
  union { float f; unsigned u; } x; x.f = f;
  unsigned r = x.u + 0x7fffu + ((x.u >> 16) & 1u);
  return (ushort)(r >> 16);
}

// packed f32x2 -> bf16x2; low word = a
__device__ __forceinline__ unsigned pk2(float a, float b) {
  __hip_bfloat162 h = __float22bfloat162_rn(float2{a, b});
  union { __hip_bfloat162 h; unsigned u; } x; x.h = h;
  return x.u;
}

__device__ __forceinline__ float blo(unsigned u) {
  union { unsigned u; float f; } x; x.u = u << 16; return x.f;
}
__device__ __forceinline__ float bhi(unsigned u) {
  union { unsigned u; float f; } x; x.u = u & 0xffff0000u; return x.f;
}

// XOR-swizzled ushort index into a [64][64] (128 B/row) LDS tile.
// byte_off within row ^= (row&7)<<4: spreads the 16B slot across 8 bank-groups.
// With pre-swizzled global staging (source 16B-slot = (l&7)^(l>>3)), data
// lands so this read index is 2-way-conflict max (free per m136).
__device__ __forceinline__ int swz64(int row, int colbyte) {
  return row * 64 + ((colbyte ^ ((row & 7) << 4)) >> 1);
}

// Single fused cast: x (1M uint4) + Wq/Wk/Wv (-> wqkv) + Wo (-> wob).
__global__ __launch_bounds__(256) void cast_all(const float* __restrict__ x,
                                                const float* __restrict__ Wq,
                                                const float* __restrict__ Wk,
                                                const float* __restrict__ Wv,
                                                const float* __restrict__ Wo,
                                                ushort* __restrict__ xb,
                                                ushort* __restrict__ wqkv,
                                                ushort* __restrict__ wob) {
  int idx = blockIdx.x * 256 + threadIdx.x;  // 0 .. 2M-1 (uint4 units)
  const float* in;
  uint2* out;
  if (idx < (1 << 20)) {
    in = x; out = (uint2*)xb;
  } else {
    int j = idx - (1 << 20);
    int w = j >> 18;            // 0..3
    idx = j & 0x3FFFF;          // 256K uint4 per weight
    switch (w) {
      case 0: in = Wq; out = (uint2*)wqkv; break;
      case 1: in = Wk; out = (uint2*)(wqkv) + (1 << 18); break;
      case 2: in = Wv; out = (uint2*)(wqkv) + (2 << 18); break;
      default: in = Wo; out = (uint2*)wob; break;
    }
  }
  float4 v = ((const float4*)in)[idx];
  uint2 o; o.x = pk2(v.x, v.y); o.y = pk2(v.z, v.w);
  out[idx] = o;
}

// Fused QKV projection: A = xb (4096x1024 bf16), Bw = wqkv (3072x1024 bf16).
// 128x128 tile, BK=64 (16 K-iters).
// R15: (a) LDS double-buffered (64 KB), ONE barrier per K-step; prefetch for
// kt+1 issued right after the barrier so its vmcnt spans the compute phase
// (same structure as attn R14). (b) 16-way bank conflict on frag reads fixed
// via pre-swizzled global source (slot (l&7)^(l>>3)) + swz64 reads.
// n<1024 -> Q (scaled), <2048 -> K, else -> V^T (packed b64 stores along t).
__global__ __launch_bounds__(256) void gemm_qkv(const ushort* __restrict__ A,
                                                const ushort* __restrict__ Bw,
                                                ushort* __restrict__ Qh,
                                                ushort* __restrict__ Kh,
                                                ushort* __restrict__ Vth,
                                                float qscale) {
  constexpr int K = 1024;
  const int bm = blockIdx.y * 128;
  const int bn = blockIdx.x * 128;
  const int tid = threadIdx.x;
  const int wave = tid >> 6;
  const int lane = tid & 63;
  const int l16 = lane & 15;
  const int quad = lane >> 4;

  __shared__ ushort As[2][128 * 64];   // 32 KB (dbuf)
  __shared__ ushort Bs[2][128 * 64];   // 32 KB (dbuf)

  const int wm = (wave & 1) * 64;
  const int wn = (wave >> 1) * 64;

  f32x4 acc[4][4];
#pragma unroll
  for (int r = 0; r < 4; ++r)
#pragma unroll
    for (int c = 0; c < 4; ++c) acc[r][c] = (f32x4){0.f, 0.f, 0.f, 0.f};

  const int srow = wave * 8 + (lane >> 3);
  const int csw = (((lane & 7) ^ (lane >> 3)) << 3);  // pre-swizzled col (ushorts)

  // prologue: tile 0 -> buf 0
#pragma unroll
  for (int j = 0; j < 4; ++j) {
    async_cp16(A  + (size_t)(bm + j * 32 + srow) * K + csw, &As[0][(j * 32 + wave * 8) * 64]);
    async_cp16(Bw + (size_t)(bn + j * 32 + srow) * K + csw, &Bs[0][(j * 32 + wave * 8) * 64]);
  }

  constexpr int NIT = K / 64;  // 16
  for (int kt = 0; kt < NIT; ++kt) {
    __syncthreads();  // vmcnt(0) drain: tile kt landed; prior reads of buf^1 done
    const int buf = kt & 1;
    if (kt + 1 < NIT) {
      const int k0 = (kt + 1) * 64;
#pragma unroll
      for (int j = 0; j < 4; ++j) {
        async_cp16(A  + (size_t)(bm + j * 32 + srow) * K + k0 + csw, &As[buf ^ 1][(j * 32 + wave * 8) * 64]);
        async_cp16(Bw + (size_t)(bn + j * 32 + srow) * K + k0 + csw, &Bs[buf ^ 1][(j * 32 + wave * 8) * 64]);
      }
    }

    bf16x8 a[2][4], b[2][4];
#pragma unroll
    for (int ks = 0; ks < 2; ++ks)
#pragma unroll
      for (int r = 0; r < 4; ++r) {
        a[ks][r] = *(const bf16x8*)(&As[buf][swz64(wm + r * 16 + l16, ks * 64 + quad * 16)]);
        b[ks][r] = *(const bf16x8*)(&Bs[buf][swz64(wn + r * 16 + l16, ks * 64 + quad * 16)]);
      }
#pragma unroll
    for (int ks = 0; ks < 2; ++ks)
#pragma unroll
      for (int r = 0; r < 4; ++r)
#pragma unroll
        for (int c = 0; c < 4; ++c)
          acc[r][c] = __builtin_amdgcn_mfma_f32_16x16x32_bf16(a[ks][r], b[ks][c], acc[r][c], 0, 0, 0);
  }

#pragma unroll
  for (int r = 0; r < 4; ++r) {
#pragma unroll
    for (int c = 0; c < 4; ++c) {
      int ncol = bn + wn + c * 16 + l16;   // 0..3071; w uniform per (block,wave)
      int w = ncol >> 10;
      int f = ncol & 1023;
      int h = f >> 6, d = f & 63;
      if (w == 2) {
        // V^T: 4 consecutive tokens per lane -> one b64 store
        int m0 = bm + wm + r * 16 + quad * 4;
        int b = m0 >> 11, t0 = m0 & 2047;
        uint2 pp;
        pp.x = pk2(acc[r][c][0], acc[r][c][1]);
        pp.y = pk2(acc[r][c][2], acc[r][c][3]);
        *(uint2*)(&Vth[((size_t)(b * 1024 + f) << 11) + t0]) = pp;
      } else {
#pragma unroll
        for (int rr = 0; rr < 4; ++rr) {
          float v = acc[r][c][rr];
          int m = bm + wm + r * 16 + quad * 4 + rr;
          int b = m >> 11, t = m & 2047;
          if (w == 0)
            Qh[((size_t)(b * 16 + h) * SEQ + t) * 64 + d] = f2b(v * qscale);
          else
            Kh[((size_t)(b * 16 + h) * SEQ + t) * 64 + d] = f2b(v);
        }
      }
    }
  }
}

// Output projection: A = ctx (4096x1024 bf16), Bw = wob, fp32 out.
// 64x128 tile, BK=64. R15: same dbuf + swizzle treatment as gemm_qkv.
__global__ __launch_bounds__(256) void gemm_out(const ushort* __restrict__ A,
                                                const ushort* __restrict__ Bw,
                                                float* __restrict__ out) {
  constexpr int K = 1024;
  const int bm = blockIdx.y * 64;
  const int bn = blockIdx.x * 128;
  const int tid = threadIdx.x;
  const int wave = tid >> 6;
  const int lane = tid & 63;
  const int l16 = lane & 15;
  const int quad = lane >> 4;

  __shared__ ushort As[2][64 * 64];    // 16 KB (dbuf)
  __shared__ ushort Bs[2][128 * 64];   // 32 KB (dbuf)

  const int wm = (wave & 1) * 32;
  const int wn = (wave >> 1) * 64;

  f32x4 acc[2][4];
#pragma unroll
  for (int r = 0; r < 2; ++r)
#pragma unroll
    for (int c = 0; c < 4; ++c) acc[r][c] = (f32x4){0.f, 0.f, 0.f, 0.f};

  const int srow = wave * 8 + (lane >> 3);
  const int csw = (((lane & 7) ^ (lane >> 3)) << 3);  // pre-swizzled col (ushorts)

  // prologue: tile 0 -> buf 0
#pragma unroll
  for (int j = 0; j < 2; ++j)
    async_cp16(A + (size_t)(bm + j * 32 + srow) * K + csw, &As[0][(j * 32 + wave * 8) * 64]);
#pragma unroll
  for (int j = 0; j < 4; ++j)
    async_cp16(Bw + (size_t)(bn + j * 32 + srow) * K + csw, &Bs[0][(j * 32 + wave * 8) * 64]);

  constexpr int NIT = K / 64;  // 16
  for (int kt = 0; kt < NIT; ++kt) {
    __syncthreads();
    const int buf = kt & 1;
    if (kt + 1 < NIT) {
      const int k0 = (kt + 1) * 64;
#pragma unroll
      for (int j = 0; j < 2; ++j)
        async_cp16(A + (size_t)(bm + j * 32 + srow) * K + k0 + csw, &As[buf ^ 1][(j * 32 + wave * 8) * 64]);
#pragma unroll
      for (int j = 0; j < 4; ++j)
        async_cp16(Bw + (size_t)(bn + j * 32 + srow) * K + k0 + csw, &Bs[buf ^ 1][(j * 32 + wave * 8) * 64]);
    }

    bf16x8 a[2][2], b[2][4];
#pragma unroll
    for (int ks = 0; ks < 2; ++ks) {
#pragma unroll
      for (int r = 0; r < 2; ++r)
        a[ks][r] = *(const bf16x8*)(&As[buf][swz64(wm + r * 16 + l16, ks * 64 + quad * 16)]);
#pragma unroll
      for (int c = 0; c < 4; ++c)
        b[ks][c] = *(const bf16x8*)(&Bs[buf][swz64(wn + c * 16 + l16, ks * 64 + quad * 16)]);
    }
#pragma unroll
    for (int ks = 0; ks < 2; ++ks)
#pragma unroll
      for (int r = 0; r < 2; ++r)
#pragma unroll
        for (int c = 0; c < 4; ++c)
          acc[r][c] = __builtin_amdgcn_mfma_f32_16x16x32_bf16(a[ks][r], b[ks][c], acc[r][c], 0, 0, 0);
  }

#pragma unroll
  for (int r = 0; r < 2; ++r)
#pragma unroll
    for (int c = 0; c < 4; ++c)
#pragma unroll
      for (int rr = 0; rr < 4; ++rr) {
        int m = bm + wm + r * 16 + quad * 4 + rr;
        int n = bn + wn + c * 16 + l16;
        out[(size_t)m * D_MODEL + n] = acc[r][c][rr];
      }
}

// Flash attention, R14 (unchanged in R15): global_load_lds staging, 1 barrier
// per K-tile, scalar-VALU l accumulation, single Pt, swizzled LDS. 40 KB LDS.
__global__ __launch_bounds__(256, 2) void attn_kernel(const ushort* __restrict__ Qh,
                                                      const ushort* __restrict__ Kh,
                                                      const ushort* __restrict__ Vth,
                                                      ushort* __restrict__ O1,
                                                      ushort* __restrict__ O2,
                                                      float* __restrict__ l1,
                                                      float* __restrict__ l2) {
  const int id = blockIdx.x;
  const int stream = id & 63;       // bh*2 + half
  const int qb = id >> 6;           // 0..15
  const int bh = stream >> 1;
  const int half = stream & 1;
  const int q0 = qb * 128;
  ushort* __restrict__ Op = half ? O2 : O1;
  float* __restrict__ lp = half ? l2 : l1;

  const int tid = threadIdx.x;
  const int wave = tid >> 6;
  const int lane = tid & 63;
  const int l16 = lane & 15;
  const int quad = lane >> 4;

  __shared__ ushort KVbuf[2][2][64 * 64];  // 32 KB: [buf][0=K,1=V^T], swizzled
  __shared__ ushort Pt[64 * 64];           // 8 KB  [q(wave*16+l16)][key], swizzled

  bf16x8 qf[2][2];
#pragma unroll
  for (int g = 0; g < 2; ++g) {
    const ushort* qp = Qh + ((size_t)bh * SEQ + q0 + wave * 32 + g * 16 + l16) * 64 + quad * 8;
    qf[g][0] = *(const bf16x8*)(qp);
    qf[g][1] = *(const bf16x8*)(qp + 32);
  }

  f32x4 o[2][4];
  float lacc[2] = {0.f, 0.f};
#pragma unroll
  for (int g = 0; g < 2; ++g)
#pragma unroll
    for (int c = 0; c < 4; ++c) o[g][c] = (f32x4){0.f, 0.f, 0.f, 0.f};

  // async staging geometry: each wave fills chunks {2w, 2w+1} (8 rows each)
  // of the 64-row tile. Lane l covers row chunk*8 + (l>>3), 16B slot (l&7).
  // Global source column is pre-swizzled: slot_src = (l&7) ^ (l>>3), so the
  // lane-linear LDS write leaves data at the swz64 position.
  const int chunk = wave * 2;
  const int r8 = lane >> 3;
  const int csw = (((lane & 7) ^ r8) << 3);   // ushort offset within 64
  const ushort* kbase = Kh + ((size_t)bh * SEQ + half * 1024) * 64;
  const ushort* vbase = Vth + (size_t)bh * 64 * SEQ + half * 1024;
  const ushort* ksrc = kbase + (size_t)(chunk * 8 + r8) * 64 + csw;   // +kt*4096
  const ushort* vsrc = vbase + (size_t)(chunk * 8 + r8) * SEQ + csw;  // +kt*64

  // prologue: tile 0 -> buf 0
  async_cp16(ksrc,           &KVbuf[0][0][chunk * 512]);
  async_cp16(ksrc + 8 * 64,  &KVbuf[0][0][(chunk + 1) * 512]);
  async_cp16(vsrc,           &KVbuf[0][1][chunk * 512]);
  async_cp16(vsrc + 8 * SEQ, &KVbuf[0][1][(chunk + 1) * 512]);

  constexpr int NIT = 1024 / 64;  // 16
  for (int kt = 0; kt < NIT; ++kt) {
    __syncthreads();  // drains vmcnt: tile kt landed; prior reads of buf^1 done
    const int buf = kt & 1;
    if (kt + 1 < NIT) {
      const ushort* ks = ksrc + (size_t)(kt + 1) * 64 * 64;
      const ushort* vs = vsrc + (kt + 1) * 64;
      async_cp16(ks,           &KVbuf[buf ^ 1][0][chunk * 512]);
      async_cp16(ks + 8 * 64,  &KVbuf[buf ^ 1][0][(chunk + 1) * 512]);
      async_cp16(vs,           &KVbuf[buf ^ 1][1][chunk * 512]);
      async_cp16(vs + 8 * SEQ, &KVbuf[buf ^ 1][1][(chunk + 1) * 512]);
    }
    const ushort* Kt = KVbuf[buf][0];
    const ushort* Vt = KVbuf[buf][1];
    const int prow = wave * 16 + l16;

    // QK^T + exp2 + pack, g-outer (single Pt buffer; same-wave in-order LDS
    // pipe orders g0 reads before g1 writes).
    bf16x8 pf[2][2];
#pragma unroll
    for (int g = 0; g < 2; ++g) {
#pragma unroll
      for (int c = 0; c < 4; ++c) {
        bf16x8 ka0 = *(const bf16x8*)(&Kt[swz64(c * 16 + l16, quad * 16)]);
        bf16x8 ka1 = *(const bf16x8*)(&Kt[swz64(c * 16 + l16, 64 + quad * 16)]);
        f32x4 z = (f32x4){0.f, 0.f, 0.f, 0.f};
        z = __builtin_amdgcn_mfma_f32_16x16x32_bf16(ka0, qf[g][0], z, 0, 0, 0);
        z = __builtin_amdgcn_mfma_f32_16x16x32_bf16(ka1, qf[g][1], z, 0, 0, 0);
        float e0 = __builtin_amdgcn_exp2f(z[0]);
        float e1 = __builtin_amdgcn_exp2f(z[1]);
        float e2 = __builtin_amdgcn_exp2f(z[2]);
        float e3 = __builtin_amdgcn_exp2f(z[3]);
        lacc[g] += (e0 + e1) + (e2 + e3);
        uint2 pp;
        pp.x = pk2(e0, e1);
        pp.y = pk2(e2, e3);
        *(uint2*)(&Pt[swz64(prow, c * 32 + quad * 8)]) = pp;
      }
      pf[g][0] = *(const bf16x8*)(&Pt[swz64(prow, quad * 16)]);
      pf[g][1] = *(const bf16x8*)(&Pt[swz64(prow, 64 + quad * 16)]);
    }

    // O += P . V
#pragma unroll
    for (int c = 0; c < 4; ++c) {
      bf16x8 vb0 = *(const bf16x8*)(&Vt[swz64(c * 16 + l16, quad * 16)]);
      bf16x8 vb1 = *(const bf16x8*)(&Vt[swz64(c * 16 + l16, 64 + quad * 16)]);
#pragma unroll
      for (int g = 0; g < 2; ++g) {
        o[g][c] = __builtin_amdgcn_mfma_f32_16x16x32_bf16(pf[g][0], vb0, o[g][c], 0, 0, 0);
        o[g][c] = __builtin_amdgcn_mfma_f32_16x16x32_bf16(pf[g][1], vb1, o[g][c], 0, 0, 0);
      }
    }
  }

  // l: cross-quad reduce (each lane has the partial over its 16 keys/iter).
#pragma unroll
  for (int g = 0; g < 2; ++g) {
    lacc[g] += __shfl_xor(lacc[g], 16, 64);
    lacc[g] += __shfl_xor(lacc[g], 32, 64);
    if (quad == 0)
      lp[(size_t)bh * SEQ + q0 + wave * 32 + g * 16 + l16] = lacc[g];
  }

  // O-store: stage the 128x64 bf16 tile into LDS (reuse KVbuf), then write
  // full 128B lines with coalesced uint4 (4 KB/instr).
  __syncthreads();  // all waves done with K/V LDS
  ushort* Ob = &KVbuf[0][0][0];  // 16 KB region
#pragma unroll
  for (int g = 0; g < 2; ++g)
#pragma unroll
    for (int r = 0; r < 4; ++r) {
      int row = wave * 32 + g * 16 + quad * 4 + r;
#pragma unroll
      for (int c = 0; c < 4; ++c)
        Ob[row * 64 + c * 16 + l16] = f2b(o[g][c][r]);
    }
  __syncthreads();  // O tile visible
  {
    uint4* dst = (uint4*)(Op + ((size_t)bh * SEQ + q0) * 64);
    const uint4* src = (const uint4*)Ob;
#pragma unroll
    for (int i = 0; i < 4; ++i)
      dst[i * 256 + tid] = src[i * 256 + tid];
  }
}

// ctx = (O1 + O2) / (l1 + l2), routed to (B, T, D_MODEL) bf16
__global__ __launch_bounds__(256) void recombine(const ushort* __restrict__ O1,
                                                 const ushort* __restrict__ O2,
                                                 const float* __restrict__ l1,
                                                 const float* __restrict__ l2,
                                                 ushort* __restrict__ ctx) {
  int idx = blockIdx.x * 256 + threadIdx.x;   // over (BH*T*64)/8 uint4 chunks
  int row = idx >> 3;                         // bh*SEQ + t
  int d8 = idx & 7;
  uint4 a = ((const uint4*)O1)[idx];
  uint4 b = ((const uint4*)O2)[idx];
  float linv = 1.f / (l1[row] + l2[row]);
  uint4 res;
  unsigned* ap = (unsigned*)&a;
  unsigned* bp = (unsigned*)&b;
  unsigned* rp = (unsigned*)&res;
#pragma unroll
  for (int i = 0; i < 4; ++i) {
    float lo = (blo(ap[i]) + blo(bp[i])) * linv;
    float hi = (bhi(ap[i]) + bhi(bp[i])) * linv;
    rp[i] = pk2(lo, hi);
  }
  int bh = row >> 11, t = row & 2047;
  int bb = bh >> 4, h = bh & 15;
  ((uint4*)ctx)[(size_t)(bb * SEQ + t) * 128 + h * 8 + d8] = res;
}

extern "C" void kernel_launch(void* const* d_in, const int* in_sizes, int n_in,
                              void* d_out, int out_size, void* d_ws, size_t ws_size,
                              hipStream_t stream) {
  const float* x  = (const float*)d_in[0];
  const float* Wq = (const float*)d_in[1];
  const float* Wk = (const float*)d_in[2];
  const float* Wv = (const float*)d_in[3];
  const float* Wo = (const float*)d_in[4];
  float* out = (float*)d_out;

  char* ws = (char*)d_ws;
  const size_t MB = 1 << 20;
  ushort* xb   = (ushort*)(ws);             // 8 MB (dead after gemm_qkv -> O2)
  ushort* wqkv = (ushort*)(ws +  8 * MB);   // 6 MB (dead after gemm_qkv -> l1/l2)
  ushort* wob  = (ushort*)(ws + 14 * MB);   // 2 MB (live until gemm_out)
  ushort* Qh   = (ushort*)(ws + 16 * MB);   // 8 MB (BH,T,64)
  ushort* Kh   = (ushort*)(ws + 24 * MB);   // 8 MB (BH,T,64)
  ushort* Vth  = (ushort*)(ws + 32 * MB);   // 8 MB (BH,64,T)
  ushort* ctx  = (ushort*)(ws + 40 * MB);   // 8 MB (B,T,D)

  // split-K partials (regions dead during attn):
  ushort* O1 = (ushort*)d_out;              // 8 MB of the 16 MB output buffer
  ushort* O2 = xb;                          // xb region, dead after gemm_qkv
  float*  l1 = (float*)wqkv;                // 256 KB
  float*  l2 = (float*)(ws + 8 * MB + 256 * 1024);

  cast_all<<<8192, 256, 0, stream>>>(x, Wq, Wk, Wv, Wo, xb, wqkv, wob);

  const float qscale = 0.125f * 1.44269504089f;  // SCALE * log2(e)
  gemm_qkv<<<dim3(3072 / 128, 4096 / 128), 256, 0, stream>>>(xb, wqkv, Qh, Kh, Vth, qscale);

  // 1D grid, 1024 blocks: id = qb*64 + (bh*2+half) -> id%8 fixed per stream
  attn_kernel<<<(SEQ / 128) * BATCH * N_HEADS * 2, 256, 0, stream>>>(
      Qh, Kh, Vth, O1, O2, l1, l2);

  recombine<<<(BATCH * N_HEADS * SEQ * 64 / 8) / 256, 256, 0, stream>>>(O1, O2, l1, l2, ctx);

  gemm_out<<<dim3(1024 / 128, 4096 / 64), 256, 0, stream>>>(ctx, wob, out);
}